// Round 3
// baseline (387.069 us; speedup 1.0000x reference)
//
#include <hip/hip_runtime.h>

// B=16, C=512, N=4096 (64x64), CP=64.
// out = gamma*(wo@softmax((wk x)(wq x)^T)@(wv x)+bo)+x
// 6-kernel bf16-MFMA pipeline:
//   k_prep:   one-shot fp32->bf16 of wq|wk|wv (fused [192][512]) and wo [512][64]
//   k_xt:     transpose+convert x -> xt bf16 [b][n][c] (BW-bound, LDS 64x64 tile,
//             XOR swizzle (c>>3)<<3: 2-way read / 4-way write conflicts only)
//   k_qkv:    pure-streaming MFMA: B-frags = 16B loads from xt, A-frags = L2-hot
//             wqkv. Waves split the 192 output rows -> acc 48 VGPR, no LDS/barriers.
//   k_energy: per-wave fp32 partials (32 splits), zero barriers
//   k_softmax: sum 32 partials + rowwise softmax -> attn bf16
//   k_avout:  attn*V (avl in LDS, swizzled) + wo-proj + bias + gamma + residual

#define NN 4096
#define CIN 512
#define CPD 64

typedef short s8v __attribute__((ext_vector_type(8)));
typedef float f4v __attribute__((ext_vector_type(4)));
typedef unsigned short u16;

__device__ __forceinline__ u16 f2bf(float f) {
    union { float f; unsigned int u; } c; c.f = f;
    unsigned int r = c.u + 0x7FFFu + ((c.u >> 16) & 1u);   // RNE
    return (u16)(r >> 16);
}

// ---------------- K0: one-shot weight convert. 128 blocks x 256 thr, 4 elems/thr.
__global__ __launch_bounds__(256) void k_prep(
    const float* __restrict__ wq, const float* __restrict__ wk,
    const float* __restrict__ wv, const float* __restrict__ wo,
    u16* __restrict__ wqkvb, u16* __restrict__ wob)
{
    const int t = blockIdx.x * 256 + threadIdx.x;   // 32768 threads
    const int i4 = t * 4;
    const float* src; u16* dst; int off;
    if (i4 < 98304) {                // 3 * 64*512
        const int r = i4 >> 15;
        src = (r == 0) ? wq : (r == 1) ? wk : wv;
        off = i4 & 32767;
        dst = wqkvb + (r << 15);
    } else {
        src = wo; off = i4 - 98304; dst = wob;
    }
    float4 v = *(const float4*)(src + off);
    u16 tmp[4] = { f2bf(v.x), f2bf(v.y), f2bf(v.z), f2bf(v.w) };
    *(uint2*)(dst + off) = *(const uint2*)tmp;
}

// ---------------- K0b: x [b][c][n] fp32 -> xt [b][n][c] bf16.
// grid (8 ctile, 64 ntile, 16 b), block 256. 64x64 tile via LDS.
__global__ __launch_bounds__(256) void k_xt(
    const float* __restrict__ x, u16* __restrict__ xt)
{
    const int ct = blockIdx.x, nt = blockIdx.y, b = blockIdx.z;
    const int t = threadIdx.x;
    const int c0 = ct * 64, n0 = nt * 64;
    __shared__ u16 lt[64 * 64];

    // phase A: coalesced float4 loads along n, swizzled LDS store
    #pragma unroll
    for (int p = 0; p < 4; ++p) {
        const int c_l = p * 16 + (t >> 4);
        const int n4  = (t & 15) * 4;
        float4 v = *(const float4*)(x + ((size_t)b * CIN + c0 + c_l) * NN + n0 + n4);
        u16 tmp[4] = { f2bf(v.x), f2bf(v.y), f2bf(v.z), f2bf(v.w) };
        *(uint2*)&lt[c_l * 64 + (n4 ^ ((c_l >> 3) << 3))] = *(const uint2*)tmp;
    }
    __syncthreads();

    // phase B: gather 8 consecutive c per thread (swizzle -> 2-way max), uint4 store
    #pragma unroll
    for (int pp = 0; pp < 2; ++pp) {
        const int n_l = pp * 32 + (t >> 3);
        const int cg  = (t & 7) * 8;
        const int swz = (t & 7) << 3;       // == ((cg+i)>>3)<<3 for i<8
        u16 tmp[8];
        #pragma unroll
        for (int i = 0; i < 8; ++i)
            tmp[i] = lt[(cg + i) * 64 + (n_l ^ swz)];
        *(uint4*)(xt + ((size_t)b * NN + n0 + n_l) * CIN + c0 + cg) =
            *(const uint4*)tmp;
    }
}

// ---------------- K1: QKV from xt. grid (64 nb, 16 b), block 256 (4 waves).
// Block tile: all 192 output rows x 64 n-cols. Wave w owns rows {p*64+w*16..+15}.
// Per K-step(32c): 4 B-frag 16B loads (xt) + 3 A-frag 16B loads (wqkv, L2-hot)
// + 12 MFMA. No LDS, no barriers.
__global__ __launch_bounds__(256, 4) void k_qkv(
    const u16* __restrict__ xt, const u16* __restrict__ wqkvb,
    const float* __restrict__ bq, const float* __restrict__ bk,
    const float* __restrict__ bv,
    u16* __restrict__ q, u16* __restrict__ k, u16* __restrict__ vt)
{
    const int nb = blockIdx.x, b = blockIdx.y;
    const int t = threadIdx.x;
    const int w = t >> 6, L = t & 63, quad = L >> 4, l15 = L & 15;
    const int n0 = nb * 64;

    f4v acc[3][4];   // [p][nn]
    #pragma unroll
    for (int p = 0; p < 3; ++p)
        #pragma unroll
        for (int nn = 0; nn < 4; ++nn) acc[p][nn] = (f4v){0.f,0.f,0.f,0.f};

    const u16* xb = xt + ((size_t)b * NN + n0) * CIN;
    const u16* wb = wqkvb + (size_t)(w * 16 + l15) * CIN;

    #pragma unroll
    for (int ks = 0; ks < 16; ++ks) {
        const int c = ks * 32 + quad * 8;
        s8v bf[4], af[3];
        #pragma unroll
        for (int nn = 0; nn < 4; ++nn)
            bf[nn] = *(const s8v*)(xb + (size_t)(nn * 16 + l15) * CIN + c);
        #pragma unroll
        for (int p = 0; p < 3; ++p)
            af[p] = *(const s8v*)(wb + (size_t)p * 64 * CIN + c);
        #pragma unroll
        for (int p = 0; p < 3; ++p)
            #pragma unroll
            for (int nn = 0; nn < 4; ++nn)
                acc[p][nn] = __builtin_amdgcn_mfma_f32_16x16x32_bf16(
                    af[p], bf[nn], acc[p][nn], 0, 0, 0);
    }

    // epilogue: rows o = w*16 + quad*4 + r (within each p-block), cols n0+nn*16+l15
    const int orow = w * 16 + quad * 4;
    {
        float4 q4 = *(const float4*)(bq + orow);
        float4 k4 = *(const float4*)(bk + orow);
        const float qb_[4] = { q4.x, q4.y, q4.z, q4.w };
        const float kb_[4] = { k4.x, k4.y, k4.z, k4.w };
        u16* qp = q + (size_t)b * CPD * NN;
        u16* kp = k + (size_t)b * CPD * NN;
        #pragma unroll
        for (int nn = 0; nn < 4; ++nn) {
            const int n = n0 + nn * 16 + l15;
            #pragma unroll
            for (int r = 0; r < 4; ++r) {
                qp[(size_t)(orow + r) * NN + n] = f2bf(acc[0][nn][r] + qb_[r]);
                kp[(size_t)(orow + r) * NN + n] = f2bf(acc[1][nn][r] + kb_[r]);
            }
        }
    }
    {
        float4 v4 = *(const float4*)(bv + orow);
        const float vb_[4] = { v4.x, v4.y, v4.z, v4.w };
        u16* vtb = vt + (size_t)b * NN * CPD;
        #pragma unroll
        for (int nn = 0; nn < 4; ++nn) {
            const int n = n0 + nn * 16 + l15;
            u16 tmp[4];
            #pragma unroll
            for (int r = 0; r < 4; ++r) tmp[r] = f2bf(acc[2][nn][r] + vb_[r]);
            *(uint2*)(vtb + (size_t)n * CPD + orow) = *(const uint2*)tmp;
        }
    }
}

// ---------------- K2: energy partials. Each WAVE owns a 128-n chunk and writes
// its own fp32 partial (32 splits per batch). No LDS, no barriers, no atomics.
__global__ __launch_bounds__(256, 4) void k_energy(
    const u16* __restrict__ q, const u16* __restrict__ k,
    float* __restrict__ epart)   // [b][32][64][64] fp32
{
    const int s = blockIdx.x;   // 8 n-chunks of 512
    const int b = blockIdx.y;
    const int t = threadIdx.x;
    const int wv_ = t >> 6, L = t & 63, quad = L >> 4, l15 = L & 15;
    const u16* kb = k + (size_t)b * CPD * NN;
    const u16* qb = q + (size_t)b * CPD * NN;

    f4v acc[4][4];
    #pragma unroll
    for (int a = 0; a < 4; ++a)
        #pragma unroll
        for (int d = 0; d < 4; ++d) acc[a][d] = (f4v){0.f,0.f,0.f,0.f};

    const int nbase = s * 512 + wv_ * 128;
    #pragma unroll
    for (int ksl = 0; ksl < 4; ++ksl) {
        const int n = nbase + ksl * 32 + quad * 8;
        s8v af[4], bf_[4];
        #pragma unroll
        for (int it = 0; it < 4; ++it)
            af[it] = *(const s8v*)(kb + (size_t)(it * 16 + l15) * NN + n);
        #pragma unroll
        for (int jt = 0; jt < 4; ++jt)
            bf_[jt] = *(const s8v*)(qb + (size_t)(jt * 16 + l15) * NN + n);
        #pragma unroll
        for (int it = 0; it < 4; ++it)
            #pragma unroll
            for (int jt = 0; jt < 4; ++jt)
                acc[it][jt] = __builtin_amdgcn_mfma_f32_16x16x32_bf16(
                    af[it], bf_[jt], acc[it][jt], 0, 0, 0);
    }

    float* ep = epart + ((size_t)b * 32 + s * 4 + wv_) * 4096;
    #pragma unroll
    for (int it = 0; it < 4; ++it)
        #pragma unroll
        for (int jt = 0; jt < 4; ++jt)
            #pragma unroll
            for (int r = 0; r < 4; ++r)
                ep[(it * 16 + quad * 4 + r) * 64 + jt * 16 + l15] =
                    acc[it][jt][r];
}

// ---------------- K3: sum 32 partials + softmax over j -> attn bf16 [b][i][j]
__global__ __launch_bounds__(64) void k_softmax(
    const float* __restrict__ epart, u16* __restrict__ attn)
{
    const int i = blockIdx.x;
    const int b = blockIdx.y;
    const int j = threadIdx.x;
    float s = 0.f;
    #pragma unroll
    for (int sp = 0; sp < 32; ++sp)
        s += epart[((size_t)b * 32 + sp) * 4096 + i * 64 + j];
    float m = s;
    #pragma unroll
    for (int off = 32; off; off >>= 1) m = fmaxf(m, __shfl_xor(m, off));
    float e = __expf(s - m);
    float tot = e;
    #pragma unroll
    for (int off = 32; off; off >>= 1) tot += __shfl_xor(tot, off);
    attn[(size_t)b * 4096 + i * 64 + j] = f2bf(e / tot);
}

// ---------------- K4: fused attn*V + out-proj + residual.
// grid (32 nb, 16 b), block 256 (4 waves, each 32 n). n-tile 128.
// phase1: D1[i][n] = attn x vt -> avl LDS [n][i] (swizzled). 16 KB LDS only.
// phase2: D2[n][c] = avl x wob (global B-frags) -> float4 epilogue along n.
__global__ __launch_bounds__(256, 4) void k_avout(
    const u16* __restrict__ vt, const u16* __restrict__ attn,
    const u16* __restrict__ wob, const float* __restrict__ bo,
    const float* __restrict__ gamma, const float* __restrict__ x,
    float* __restrict__ out)
{
    const int nb = blockIdx.x, b = blockIdx.y;
    const int t = threadIdx.x;
    const int wv_ = t >> 6, L = t & 63, quad = L >> 4, l15 = L & 15;
    const int swz = (l15 & 7) * 8;

    __shared__ u16 avl[128 * 64];   // [n][i], swizzled, 16 KB

    // phase 1: avt tile (128 n-cols), A = attn (global), B = vt (global)
    {
        const u16* ab  = attn + (size_t)b * 4096;
        const u16* vtb = vt + (size_t)b * NN * CPD;
        const int n0 = nb * 128;
        f4v acc1[4][2];   // [it][ntc]
        #pragma unroll
        for (int a = 0; a < 4; ++a)
            #pragma unroll
            for (int d = 0; d < 2; ++d) acc1[a][d] = (f4v){0.f,0.f,0.f,0.f};
        #pragma unroll
        for (int ks = 0; ks < 2; ++ks) {
            const int j = ks * 32 + quad * 8;
            s8v af[4], bf_[2];
            #pragma unroll
            for (int it = 0; it < 4; ++it)
                af[it] = *(const s8v*)(ab + (size_t)(it * 16 + l15) * 64 + j);
            #pragma unroll
            for (int nn = 0; nn < 2; ++nn)
                bf_[nn] = *(const s8v*)(vtb +
                    (size_t)(n0 + wv_ * 32 + nn * 16 + l15) * CPD + j);
            #pragma unroll
            for (int it = 0; it < 4; ++it)
                #pragma unroll
                for (int nn = 0; nn < 2; ++nn)
                    acc1[it][nn] = __builtin_amdgcn_mfma_f32_16x16x32_bf16(
                        af[it], bf_[nn], acc1[it][nn], 0, 0, 0);
        }
        #pragma unroll
        for (int it = 0; it < 4; ++it)
            #pragma unroll
            for (int nn = 0; nn < 2; ++nn) {
                const int nloc = wv_ * 32 + nn * 16 + l15;
                u16 tmp[4];
                #pragma unroll
                for (int r = 0; r < 4; ++r) tmp[r] = f2bf(acc1[it][nn][r]);
                *(uint2*)&avl[nloc * 64 + ((it * 16 + quad * 4) ^ swz)] =
                    *(const uint2*)tmp;
            }
    }
    __syncthreads();

    // phase 2: out = gamma*(wo@av + bo) + x, float4 along n
    const float g = gamma[0];
    const int n0 = nb * 128;
    for (int cb = 0; cb < 8; ++cb) {
        f4v acc2[2][4];   // [nt][ct]
        #pragma unroll
        for (int a = 0; a < 2; ++a)
            #pragma unroll
            for (int d = 0; d < 4; ++d) acc2[a][d] = (f4v){0.f,0.f,0.f,0.f};
        #pragma unroll
        for (int ks = 0; ks < 2; ++ks) {
            const int i0 = ks * 32 + quad * 8;
            const int ic = i0 ^ swz;
            s8v af2[2], bf2[4];
            #pragma unroll
            for (int nt = 0; nt < 2; ++nt)
                af2[nt] = *(const s8v*)&avl[(wv_ * 32 + nt * 16 + l15) * 64 + ic];
            #pragma unroll
            for (int ct = 0; ct < 4; ++ct)
                bf2[ct] = *(const s8v*)(wob +
                    (size_t)(cb * 64 + ct * 16 + l15) * CPD + i0);
            #pragma unroll
            for (int nt = 0; nt < 2; ++nt)
                #pragma unroll
                for (int ct = 0; ct < 4; ++ct)
                    acc2[nt][ct] = __builtin_amdgcn_mfma_f32_16x16x32_bf16(
                        af2[nt], bf2[ct], acc2[nt][ct], 0, 0, 0);
        }
        // D2 rows n = n0+wv_*32+nt*16+quad*4+r, cols c = cb*64+ct*16+l15
        #pragma unroll
        for (int nt = 0; nt < 2; ++nt)
            #pragma unroll
            for (int ct = 0; ct < 4; ++ct) {
                const int c = cb * 64 + ct * 16 + l15;
                const float bs = bo[c];
                const int nbase = n0 + wv_ * 32 + nt * 16 + quad * 4;
                const size_t idx = ((size_t)b * CIN + c) * NN + nbase;
                float4 xr = *(const float4*)(x + idx);
                float4 r4;
                r4.x = g * (acc2[nt][ct][0] + bs) + xr.x;
                r4.y = g * (acc2[nt][ct][1] + bs) + xr.y;
                r4.z = g * (acc2[nt][ct][2] + bs) + xr.z;
                r4.w = g * (acc2[nt][ct][3] + bs) + xr.w;
                *(float4*)(out + idx) = r4;
            }
    }
}

extern "C" void kernel_launch(void* const* d_in, const int* in_sizes, int n_in,
                              void* d_out, int out_size, void* d_ws, size_t ws_size,
                              hipStream_t stream) {
    const float* x  = (const float*)d_in[0];
    const float* wq = (const float*)d_in[1];
    const float* bq = (const float*)d_in[2];
    const float* wk = (const float*)d_in[3];
    const float* bk = (const float*)d_in[4];
    const float* wv = (const float*)d_in[5];
    const float* bv = (const float*)d_in[6];
    const float* wo = (const float*)d_in[7];
    const float* bo = (const float*)d_in[8];
    const float* gm = (const float*)d_in[9];
    float* out = (float*)d_out;

    // workspace (bytes), total ~101 MB:
    char* wsb = (char*)d_ws;
    u16*   xt    = (u16*)wsb;                         // 67.11 MB [b][n][c]
    u16*   q     = (u16*)(wsb + 67108864);            //  8.39 MB [b][cp][n]
    u16*   k     = (u16*)(wsb + 75497472);            //  8.39 MB [b][cp][n]
    u16*   vt    = (u16*)(wsb + 83886080);            //  8.39 MB [b][n][cp]
    float* epart = (float*)(wsb + 92274688);          //  8.39 MB [b][32][64][64]
    u16*   attn  = (u16*)(wsb + 100663296);           //  0.13 MB [b][64][64]
    u16*   wqkvb = (u16*)(wsb + 100794368);           //  0.20 MB [192][512]
    u16*   wob   = (u16*)(wsb + 100990976);           //  0.06 MB [512][64]

    k_prep<<<128, 256, 0, stream>>>(wq, wk, wv, wo, wqkvb, wob);
    k_xt<<<dim3(8, 64, 16), 256, 0, stream>>>(x, xt);
    k_qkv<<<dim3(64, 16), 256, 0, stream>>>(xt, wqkvb, bq, bk, bv, q, k, vt);
    k_energy<<<dim3(8, 16), 256, 0, stream>>>(q, k, epart);
    k_softmax<<<dim3(64, 16), 64, 0, stream>>>(epart, attn);
    k_avout<<<dim3(32, 16), 256, 0, stream>>>(vt, attn, wob, bo, gm, x, out);
}

// Round 4
// 346.560 us; speedup vs baseline: 1.1169x; 1.1169x over previous
//
#include <hip/hip_runtime.h>

// B=16, C=512, N=4096 (64x64), CP=64.
// out = gamma*(wo@softmax((wk x)(wq x)^T)@(wv x)+bo)+x
// 5-kernel bf16-MFMA pipeline, transpose fused into QKV via LDS:
//   k_prep:   one-shot fp32->bf16 of wq|wk|wv (fused [192][512]) and wo [512][64]
//   k_qkv:    reads x ONCE. Per 64c-chunk: coalesced dword loads -> regs ->
//             LDS [n][c] bf16 (c4-slot XOR swizzle, dbuf, issue-early/write-late).
//             B-frags = 2x ds_read_b64; A-frags = L2-hot wqkv. -> q,k [cp][n], vt [n][cp]
//   k_energy: per-wave fp32 partials (32 splits), zero barriers
//   k_softmax: sum 32 partials + rowwise softmax -> attn bf16
//   k_avout:  attn*V (avl in LDS, swizzled) + wo-proj + bias + gamma + residual,
//             n-tile 64, 4 blocks/CU.

#define NN 4096
#define CIN 512
#define CPD 64

typedef short s8v __attribute__((ext_vector_type(8)));
typedef float f4v __attribute__((ext_vector_type(4)));
typedef unsigned short u16;

__device__ __forceinline__ u16 f2bf(float f) {
    union { float f; unsigned int u; } c; c.f = f;
    unsigned int r = c.u + 0x7FFFu + ((c.u >> 16) & 1u);   // RNE
    return (u16)(r >> 16);
}

union PK { uint2 u[2]; s8v v; };

// ---------------- K0: one-shot weight convert. 128 blocks x 256 thr, 4 elems/thr.
__global__ __launch_bounds__(256) void k_prep(
    const float* __restrict__ wq, const float* __restrict__ wk,
    const float* __restrict__ wv, const float* __restrict__ wo,
    u16* __restrict__ wqkvb, u16* __restrict__ wob)
{
    const int t = blockIdx.x * 256 + threadIdx.x;   // 32768 threads
    const int i4 = t * 4;
    const float* src; u16* dst; int off;
    if (i4 < 98304) {                // 3 * 64*512
        const int r = i4 >> 15;
        src = (r == 0) ? wq : (r == 1) ? wk : wv;
        off = i4 & 32767;
        dst = wqkvb + (r << 15);
    } else {
        src = wo; off = i4 - 98304; dst = wob;
    }
    float4 v = *(const float4*)(src + off);
    u16 tmp[4] = { f2bf(v.x), f2bf(v.y), f2bf(v.z), f2bf(v.w) };
    *(uint2*)(dst + off) = *(const uint2*)tmp;
}

// ---------------- K1: QKV with fused transpose. grid (64 nb, 16 b), block 256
// (4 waves). Block tile: 192 output rows x 64 n-cols, K = 512 in 8 chunks of 64.
// LDS chunk layout: row n (0..63), 16 slots of 4 c each; slot = c4 ^ (n&15).
// Wave w owns output rows {p*64 + w*16 .. +15} for p = q,k,v.
__global__ __launch_bounds__(256, 4) void k_qkv(
    const float* __restrict__ x, const u16* __restrict__ wqkvb,
    const float* __restrict__ bq, const float* __restrict__ bk,
    const float* __restrict__ bv,
    u16* __restrict__ q, u16* __restrict__ k, u16* __restrict__ vt)
{
    const int nb = blockIdx.x, b = blockIdx.y;
    const int t = threadIdx.x;
    const int w = t >> 6, L = t & 63, quad = L >> 4, l15 = L & 15;
    const int n0 = nb * 64;

    __shared__ u16 xs[2][64 * 64];   // dbuf, 16 KB total

    // staging role: this thread loads column n0+nl, c4-groups c4b, c4b+4, c4b+8, c4b+12
    const int nl = t & 63, c4b = t >> 6;
    const float* xp = x + (size_t)b * CIN * NN + n0 + nl;

    f4v acc[3][4];   // [p][nn]
    #pragma unroll
    for (int p = 0; p < 3; ++p)
        #pragma unroll
        for (int nn = 0; nn < 4; ++nn) acc[p][nn] = (f4v){0.f,0.f,0.f,0.f};

    const u16* wb = wqkvb + (size_t)(w * 16 + l15) * CIN;

    float xr[16];
    // prologue: load + stage chunk 0
    #pragma unroll
    for (int i = 0; i < 4; ++i)
        #pragma unroll
        for (int j = 0; j < 4; ++j)
            xr[i * 4 + j] = xp[(size_t)((c4b + 4 * i) * 4 + j) * NN];
    #pragma unroll
    for (int i = 0; i < 4; ++i) {
        u16 t4[4];
        #pragma unroll
        for (int j = 0; j < 4; ++j) t4[j] = f2bf(xr[i * 4 + j]);
        const int slot = (c4b + 4 * i) ^ (nl & 15);
        *(uint2*)&xs[0][nl * 64 + slot * 4] = *(const uint2*)t4;
    }
    __syncthreads();

    for (int cc = 0; cc < 8; ++cc) {
        const int buf = cc & 1;
        // issue next chunk's global loads early (latency hides under MFMA)
        if (cc < 7) {
            const int c0n = (cc + 1) * 64;
            #pragma unroll
            for (int i = 0; i < 4; ++i)
                #pragma unroll
                for (int j = 0; j < 4; ++j)
                    xr[i * 4 + j] = xp[(size_t)(c0n + (c4b + 4 * i) * 4 + j) * NN];
        }
        // compute chunk cc: 2 K-steps of 32 c
        #pragma unroll
        for (int ks2 = 0; ks2 < 2; ++ks2) {
            s8v bf[4];
            #pragma unroll
            for (int nn = 0; nn < 4; ++nn) {
                const int row = nn * 16 + l15;
                const int sb = ks2 * 8 + quad * 2;
                PK p_;
                p_.u[0] = *(const uint2*)&xs[buf][row * 64 + ((sb ^ l15) * 4)];
                p_.u[1] = *(const uint2*)&xs[buf][row * 64 + (((sb + 1) ^ l15) * 4)];
                bf[nn] = p_.v;
            }
            const int cgl = cc * 64 + ks2 * 32 + quad * 8;
            #pragma unroll
            for (int p = 0; p < 3; ++p) {
                s8v af = *(const s8v*)(wb + (size_t)p * 64 * CIN + cgl);
                #pragma unroll
                for (int nn = 0; nn < 4; ++nn)
                    acc[p][nn] = __builtin_amdgcn_mfma_f32_16x16x32_bf16(
                        af, bf[nn], acc[p][nn], 0, 0, 0);
            }
        }
        // write next chunk into the other buffer
        if (cc < 7) {
            #pragma unroll
            for (int i = 0; i < 4; ++i) {
                u16 t4[4];
                #pragma unroll
                for (int j = 0; j < 4; ++j) t4[j] = f2bf(xr[i * 4 + j]);
                const int slot = (c4b + 4 * i) ^ (nl & 15);
                *(uint2*)&xs[buf ^ 1][nl * 64 + slot * 4] = *(const uint2*)t4;
            }
        }
        __syncthreads();
    }

    // epilogue: rows o = w*16 + quad*4 + r (within each p-block), cols n0+nn*16+l15
    const int orow = w * 16 + quad * 4;
    {
        float4 q4 = *(const float4*)(bq + orow);
        float4 k4 = *(const float4*)(bk + orow);
        const float qb_[4] = { q4.x, q4.y, q4.z, q4.w };
        const float kb_[4] = { k4.x, k4.y, k4.z, k4.w };
        u16* qp = q + (size_t)b * CPD * NN;
        u16* kp = k + (size_t)b * CPD * NN;
        #pragma unroll
        for (int nn = 0; nn < 4; ++nn) {
            const int n = n0 + nn * 16 + l15;
            #pragma unroll
            for (int r = 0; r < 4; ++r) {
                qp[(size_t)(orow + r) * NN + n] = f2bf(acc[0][nn][r] + qb_[r]);
                kp[(size_t)(orow + r) * NN + n] = f2bf(acc[1][nn][r] + kb_[r]);
            }
        }
    }
    {
        float4 v4 = *(const float4*)(bv + orow);
        const float vb_[4] = { v4.x, v4.y, v4.z, v4.w };
        u16* vtb = vt + (size_t)b * NN * CPD;
        #pragma unroll
        for (int nn = 0; nn < 4; ++nn) {
            const int n = n0 + nn * 16 + l15;
            u16 tmp[4];
            #pragma unroll
            for (int r = 0; r < 4; ++r) tmp[r] = f2bf(acc[2][nn][r] + vb_[r]);
            *(uint2*)(vtb + (size_t)n * CPD + orow) = *(const uint2*)tmp;
        }
    }
}

// ---------------- K2: energy partials. Each WAVE owns a 128-n chunk and writes
// its own fp32 partial (32 splits per batch). No LDS, no barriers, no atomics.
__global__ __launch_bounds__(256, 4) void k_energy(
    const u16* __restrict__ q, const u16* __restrict__ k,
    float* __restrict__ epart)   // [b][32][64][64] fp32
{
    const int s = blockIdx.x;   // 8 n-chunks of 512
    const int b = blockIdx.y;
    const int t = threadIdx.x;
    const int wv_ = t >> 6, L = t & 63, quad = L >> 4, l15 = L & 15;
    const u16* kb = k + (size_t)b * CPD * NN;
    const u16* qb = q + (size_t)b * CPD * NN;

    f4v acc[4][4];
    #pragma unroll
    for (int a = 0; a < 4; ++a)
        #pragma unroll
        for (int d = 0; d < 4; ++d) acc[a][d] = (f4v){0.f,0.f,0.f,0.f};

    const int nbase = s * 512 + wv_ * 128;
    #pragma unroll
    for (int ksl = 0; ksl < 4; ++ksl) {
        const int n = nbase + ksl * 32 + quad * 8;
        s8v af[4], bf_[4];
        #pragma unroll
        for (int it = 0; it < 4; ++it)
            af[it] = *(const s8v*)(kb + (size_t)(it * 16 + l15) * NN + n);
        #pragma unroll
        for (int jt = 0; jt < 4; ++jt)
            bf_[jt] = *(const s8v*)(qb + (size_t)(jt * 16 + l15) * NN + n);
        #pragma unroll
        for (int it = 0; it < 4; ++it)
            #pragma unroll
            for (int jt = 0; jt < 4; ++jt)
                acc[it][jt] = __builtin_amdgcn_mfma_f32_16x16x32_bf16(
                    af[it], bf_[jt], acc[it][jt], 0, 0, 0);
    }

    float* ep = epart + ((size_t)b * 32 + s * 4 + wv_) * 4096;
    #pragma unroll
    for (int it = 0; it < 4; ++it)
        #pragma unroll
        for (int jt = 0; jt < 4; ++jt)
            #pragma unroll
            for (int r = 0; r < 4; ++r)
                ep[(it * 16 + quad * 4 + r) * 64 + jt * 16 + l15] =
                    acc[it][jt][r];
}

// ---------------- K3: sum 32 partials + softmax over j -> attn bf16 [b][i][j]
__global__ __launch_bounds__(64) void k_softmax(
    const float* __restrict__ epart, u16* __restrict__ attn)
{
    const int i = blockIdx.x;
    const int b = blockIdx.y;
    const int j = threadIdx.x;
    float s = 0.f;
    #pragma unroll
    for (int sp = 0; sp < 32; ++sp)
        s += epart[((size_t)b * 32 + sp) * 4096 + i * 64 + j];
    float m = s;
    #pragma unroll
    for (int off = 32; off; off >>= 1) m = fmaxf(m, __shfl_xor(m, off));
    float e = __expf(s - m);
    float tot = e;
    #pragma unroll
    for (int off = 32; off; off >>= 1) tot += __shfl_xor(tot, off);
    attn[(size_t)b * 4096 + i * 64 + j] = f2bf(e / tot);
}

// ---------------- K4: fused attn*V + out-proj + residual.
// grid (64 nb, 16 b), block 256 (4 waves, each 16 n). n-tile 64, 8 KB LDS.
// phase1: D1[i][n] = attn x vt -> avl LDS [n][i] (c4-slot XOR swizzle).
// phase2: D2[n][c] = avl x wob (global B-frags) -> float4 epilogue along n.
__global__ __launch_bounds__(256, 4) void k_avout(
    const u16* __restrict__ vt, const u16* __restrict__ attn,
    const u16* __restrict__ wob, const float* __restrict__ bo,
    const float* __restrict__ gamma, const float* __restrict__ x,
    float* __restrict__ out)
{
    const int nb = blockIdx.x, b = blockIdx.y;
    const int t = threadIdx.x;
    const int wv_ = t >> 6, L = t & 63, quad = L >> 4, l15 = L & 15;
    const int n0 = nb * 64;

    __shared__ u16 avl[64 * 64];   // [n][i], slot-swizzled, 8 KB

    // phase 1: D1[i 0..63][n-local: wave covers wv_*16 + l15]
    {
        const u16* ab  = attn + (size_t)b * 4096;
        const u16* vtb = vt + (size_t)b * NN * CPD;
        f4v acc1[4];
        #pragma unroll
        for (int a = 0; a < 4; ++a) acc1[a] = (f4v){0.f,0.f,0.f,0.f};
        const int nloc = wv_ * 16 + l15;
        #pragma unroll
        for (int ks = 0; ks < 2; ++ks) {
            const int j = ks * 32 + quad * 8;
            s8v bfv = *(const s8v*)(vtb + (size_t)(n0 + nloc) * CPD + j);
            #pragma unroll
            for (int it = 0; it < 4; ++it) {
                s8v af = *(const s8v*)(ab + (size_t)(it * 16 + l15) * 64 + j);
                acc1[it] = __builtin_amdgcn_mfma_f32_16x16x32_bf16(
                    af, bfv, acc1[it], 0, 0, 0);
            }
        }
        // lane holds D1[i = it*16+quad*4+r][n-local = nloc]; write avl[n][i]
        #pragma unroll
        for (int it = 0; it < 4; ++it) {
            u16 t4[4];
            #pragma unroll
            for (int r = 0; r < 4; ++r) t4[r] = f2bf(acc1[it][r]);
            const int slot = (it * 4 + quad) ^ l15;
            *(uint2*)&avl[nloc * 64 + slot * 4] = *(const uint2*)t4;
        }
    }
    __syncthreads();

    // phase 2: out = gamma*(wo@av + bo) + x, float4 along n
    const float g = gamma[0];
    for (int cb = 0; cb < 8; ++cb) {
        f4v acc2[4];   // [ct]
        #pragma unroll
        for (int a = 0; a < 4; ++a) acc2[a] = (f4v){0.f,0.f,0.f,0.f};
        #pragma unroll
        for (int ks = 0; ks < 2; ++ks) {
            // A-frag: row n-local = wv_*16 + l15, k = i = ks*32 + quad*8 ..+7
            const int sb = ks * 8 + quad * 2;
            PK p_;
            p_.u[0] = *(const uint2*)&avl[(wv_ * 16 + l15) * 64 + ((sb ^ l15) * 4)];
            p_.u[1] = *(const uint2*)&avl[(wv_ * 16 + l15) * 64 + (((sb + 1) ^ l15) * 4)];
            const s8v af2 = p_.v;
            const int i0 = ks * 32 + quad * 8;
            #pragma unroll
            for (int ct = 0; ct < 4; ++ct) {
                s8v bf2 = *(const s8v*)(wob +
                    (size_t)(cb * 64 + ct * 16 + l15) * CPD + i0);
                acc2[ct] = __builtin_amdgcn_mfma_f32_16x16x32_bf16(
                    af2, bf2, acc2[ct], 0, 0, 0);
            }
        }
        // D2 rows n = n0 + wv_*16 + quad*4 + r, cols c = cb*64 + ct*16 + l15
        #pragma unroll
        for (int ct = 0; ct < 4; ++ct) {
            const int c = cb * 64 + ct * 16 + l15;
            const float bs = bo[c];
            const int nb4 = n0 + wv_ * 16 + quad * 4;
            const size_t idx = ((size_t)b * CIN + c) * NN + nb4;
            float4 xr = *(const float4*)(x + idx);
            float4 r4;
            r4.x = g * (acc2[ct][0] + bs) + xr.x;
            r4.y = g * (acc2[ct][1] + bs) + xr.y;
            r4.z = g * (acc2[ct][2] + bs) + xr.z;
            r4.w = g * (acc2[ct][3] + bs) + xr.w;
            *(float4*)(out + idx) = r4;
        }
    }
}

extern "C" void kernel_launch(void* const* d_in, const int* in_sizes, int n_in,
                              void* d_out, int out_size, void* d_ws, size_t ws_size,
                              hipStream_t stream) {
    const float* x  = (const float*)d_in[0];
    const float* wq = (const float*)d_in[1];
    const float* bq = (const float*)d_in[2];
    const float* wk = (const float*)d_in[3];
    const float* bk = (const float*)d_in[4];
    const float* wv = (const float*)d_in[5];
    const float* bv = (const float*)d_in[6];
    const float* wo = (const float*)d_in[7];
    const float* bo = (const float*)d_in[8];
    const float* gm = (const float*)d_in[9];
    float* out = (float*)d_out;

    // workspace (bytes), total ~34 MB:
    char* wsb = (char*)d_ws;
    u16*   q     = (u16*)wsb;                         //  8.39 MB [b][cp][n]
    u16*   k     = (u16*)(wsb + 8388608);             //  8.39 MB [b][cp][n]
    u16*   vt    = (u16*)(wsb + 16777216);            //  8.39 MB [b][n][cp]
    float* epart = (float*)(wsb + 25165824);          //  8.39 MB [b][32][64][64]
    u16*   attn  = (u16*)(wsb + 33554432);            //  0.13 MB [b][64][64]
    u16*   wqkvb = (u16*)(wsb + 33685504);            //  0.20 MB [192][512]
    u16*   wob   = (u16*)(wsb + 33882112);            //  0.06 MB [512][64]

    k_prep<<<128, 256, 0, stream>>>(wq, wk, wv, wo, wqkvb, wob);
    k_qkv<<<dim3(64, 16), 256, 0, stream>>>(x, wqkvb, bq, bk, bv, q, k, vt);
    k_energy<<<dim3(8, 16), 256, 0, stream>>>(q, k, epart);
    k_softmax<<<dim3(64, 16), 64, 0, stream>>>(epart, attn);
    k_avout<<<dim3(64, 16), 256, 0, stream>>>(vt, attn, wob, bo, gm, x, out);
}